// Round 1
// 532.329 us; speedup vs baseline: 1.0016x; 1.0016x over previous
//
#include <hip/hip_runtime.h>

// TokenCombiner: row-shuffling copy (MoE token combine, single rank).
// For each output row r: j = max{k : out_off[k] <= r}; pos = r - out_off[j];
// if pos < out_splits[j]: out[r] = inp[clip(in_off[j]+pos)], else out[r] = outbuf[r].
//
// Memory-bound: 256 MiB read + 256 MiB write -> ~85-90 us floor at 6.3 TB/s.
//
// This version vs previous:
//  - hidden4 is a compile-time constant (1024) -> copy fully unrolled, no
//    dependent load->store loop.
//  - 8 rows per block (grid = 2048, ~8 blocks/CU, 32 waves/CU) -> 512 B/thread,
//    loads issued in independent batches of 4 before the stores (ILP).
//  - non-temporal loads/stores: pure streaming, zero reuse, keep L2 clean.

typedef float f4 __attribute__((ext_vector_type(4)));

constexpr int H4  = 1024;  // hidden/4, hidden = 4096 fixed by the problem
constexpr int RPB = 8;     // rows per block
constexpr int TPB = 256;   // threads per block

__global__ __launch_bounds__(TPB) void TokenCombiner_70523363000736_kernel(
    const f4* __restrict__ inp,      // [in_rows, H4]
    const f4* __restrict__ outbuf,   // [out_rows, H4] passthrough values
    const int* __restrict__ in_so,   // [2, nsplits]: row0=splits, row1=in_off
    const int* __restrict__ out_so,  // [2, nsplits]: row0=splits, row1=out_off
    f4*       __restrict__ out,      // [out_rows, H4]
    int nsplits, int in_rows, int out_rows)
{
    const int r0 = blockIdx.x * RPB;
    const int t  = threadIdx.x;

    const int* out_splits = out_so;
    const int* out_off    = out_so + nsplits;
    const int* in_off     = in_so  + nsplits;

    #pragma unroll
    for (int i = 0; i < RPB; ++i) {
        const int row = r0 + i;
        if (row < out_rows) {
            // searchsorted(out_off, row, 'right') - 1, clipped to [0, nsplits-1].
            // nsplits is tiny (8); linear scan, block-uniform.
            int j = 0;
            for (int k = 1; k < nsplits; ++k)
                if (out_off[k] <= row) j = k;

            const int  pos   = row - out_off[j];
            const bool valid = pos < out_splits[j];

            long src = (long)in_off[j] + (long)pos;
            if (src < 0) src = 0;
            if (src > (long)(in_rows - 1)) src = (long)(in_rows - 1);

            const f4* __restrict__ s = valid ? (inp + src * (long)H4)
                                             : (outbuf + (long)row * (long)H4);
            f4* __restrict__ d = out + (long)row * (long)H4;

            // 4 independent 16 B loads in flight, then 4 stores. Coalesced:
            // each wave's 64 lanes cover a contiguous 1 KiB segment.
            f4 v0 = __builtin_nontemporal_load(&s[t + 0 * TPB]);
            f4 v1 = __builtin_nontemporal_load(&s[t + 1 * TPB]);
            f4 v2 = __builtin_nontemporal_load(&s[t + 2 * TPB]);
            f4 v3 = __builtin_nontemporal_load(&s[t + 3 * TPB]);
            __builtin_nontemporal_store(v0, &d[t + 0 * TPB]);
            __builtin_nontemporal_store(v1, &d[t + 1 * TPB]);
            __builtin_nontemporal_store(v2, &d[t + 2 * TPB]);
            __builtin_nontemporal_store(v3, &d[t + 3 * TPB]);
        }
    }
}

extern "C" void kernel_launch(void* const* d_in, const int* in_sizes, int n_in,
                              void* d_out, int out_size, void* d_ws, size_t ws_size,
                              hipStream_t stream) {
    const f4*  inp    = (const f4*)d_in[0];
    const f4*  outbuf = (const f4*)d_in[1];
    const int* in_so  = (const int*)d_in[2];
    const int* out_so = (const int*)d_in[3];
    f4*        out    = (f4*)d_out;

    const int hidden   = 4096;                 // fixed by problem (HIDDEN); H4 = hidden/4
    const int nsplits  = in_sizes[2] / 2;      // [2, nsplits] stacked
    const int in_rows  = in_sizes[0] / hidden;
    const int out_rows = out_size   / hidden;

    const int grid = (out_rows + RPB - 1) / RPB;

    TokenCombiner_70523363000736_kernel<<<grid, TPB, 0, stream>>>(
        inp, outbuf, in_so, out_so, out, nsplits, in_rows, out_rows);
}